// Round 1
// baseline (105439.368 us; speedup 1.0000x reference)
//
#include <hip/hip_runtime.h>
#include <cstdint>

#define T_STEPS 8192
#define HDIM    768
#define G3      2304   // 3*H
#define NDR     4608   // 2*3*H
#define HC      1536   // 2*H
#define NWG     96     // grid barrier size for recurrence
#define GPD     48     // workgroups per direction
#define C_ROWS  16     // h-rows per workgroup

// ---------------------------------------------------------------------------
// GEMM: C[m][n] = sum_k X[m][k] * W[n][k] + bias[n]
// X: [M,K] row-major, W: [N,K] row-major (i.e. weight rows are K-contiguous)
// M=8192, N=4608, K in {512,1536}; all divisible by tile dims -> no bounds.
// 128x128 tile, BK=16, 256 threads, 8x8 micro-tile.
// ---------------------------------------------------------------------------
__global__ __launch_bounds__(256)
void gemm_xwt(const float* __restrict__ X, const float* __restrict__ W,
              const float* __restrict__ bias, float* __restrict__ C,
              int M, int N, int K) {
    __shared__ float As[16][132];
    __shared__ float Bs[16][132];
    const int tid = threadIdx.x;
    const int m0 = blockIdx.y * 128;
    const int n0 = blockIdx.x * 128;
    const int tm = tid >> 4;   // 0..15
    const int tn = tid & 15;   // 0..15

    float acc[8][8] = {};

    for (int k0 = 0; k0 < K; k0 += 16) {
        #pragma unroll
        for (int l = 0; l < 2; ++l) {
            int idx = l * 256 + tid;        // 0..511
            int row = idx >> 2;             // 0..127
            int kc  = (idx & 3) << 2;       // 0,4,8,12
            float4 a = *(const float4*)(X + (size_t)(m0 + row) * K + k0 + kc);
            As[kc + 0][row] = a.x; As[kc + 1][row] = a.y;
            As[kc + 2][row] = a.z; As[kc + 3][row] = a.w;
            float4 b = *(const float4*)(W + (size_t)(n0 + row) * K + k0 + kc);
            Bs[kc + 0][row] = b.x; Bs[kc + 1][row] = b.y;
            Bs[kc + 2][row] = b.z; Bs[kc + 3][row] = b.w;
        }
        __syncthreads();
        #pragma unroll
        for (int k = 0; k < 16; ++k) {
            float4 a0 = *(const float4*)&As[k][tm * 8];
            float4 a1 = *(const float4*)&As[k][tm * 8 + 4];
            float4 b0 = *(const float4*)&Bs[k][tn * 8];
            float4 b1 = *(const float4*)&Bs[k][tn * 8 + 4];
            float av[8] = {a0.x, a0.y, a0.z, a0.w, a1.x, a1.y, a1.z, a1.w};
            float bv[8] = {b0.x, b0.y, b0.z, b0.w, b1.x, b1.y, b1.z, b1.w};
            #pragma unroll
            for (int i = 0; i < 8; ++i)
                #pragma unroll
                for (int j = 0; j < 8; ++j)
                    acc[i][j] = fmaf(av[i], bv[j], acc[i][j]);
        }
        __syncthreads();
    }

    float bfrag[8];
    #pragma unroll
    for (int j = 0; j < 8; ++j) bfrag[j] = bias[n0 + tn * 8 + j];

    #pragma unroll
    for (int i = 0; i < 8; ++i) {
        float* cp = C + (size_t)(m0 + tm * 8 + i) * N + n0 + tn * 8;
        float4 o0, o1;
        o0.x = acc[i][0] + bfrag[0]; o0.y = acc[i][1] + bfrag[1];
        o0.z = acc[i][2] + bfrag[2]; o0.w = acc[i][3] + bfrag[3];
        o1.x = acc[i][4] + bfrag[4]; o1.y = acc[i][5] + bfrag[5];
        o1.z = acc[i][6] + bfrag[6]; o1.w = acc[i][7] + bfrag[7];
        *(float4*)(cp + 0) = o0;
        *(float4*)(cp + 4) = o1;
    }
}

// ---------------------------------------------------------------------------
// GRU recurrence for one layer (both directions), persistent kernel.
// Grid = 96 WGs x 256 threads (all co-resident on 256 CUs; custom barrier).
// WG (d, chunk): owns rows j0..j0+15 of direction d. 48 dot-products
// (3 gates x 16 rows) of length 768; weights register-resident
// (12 dots/wave x 3 float4 = 144 VGPRs/lane).
// Gi: [T][2][2304] precomputed (includes b_ih). bhh added here (n-gate needs
// b_hh inside r*(.)). Hout: [T][2][768].
// ---------------------------------------------------------------------------
__device__ __forceinline__ float dot4(float4 a, float4 b) {
    return a.x * b.x + a.y * b.y + a.z * b.z + a.w * b.w;
}
__device__ __forceinline__ float sigf(float x) {
    return 1.0f / (1.0f + expf(-x));
}

__global__ __launch_bounds__(256, 1)
void gru_rec(const float* __restrict__ Gi,   // [T][2][2304]
             const float* __restrict__ whh,  // [2][2304][768]
             const float* __restrict__ bhh,  // [2][2304]
             const float* __restrict__ h0,   // [2][768] (layer slice of h0)
             float* __restrict__ hb0,        // [2][768] ping
             float* __restrict__ hb1,        // [2][768] pong
             float* __restrict__ Hout,       // [T][2][768]
             unsigned* __restrict__ bar_cnt,
             unsigned* __restrict__ bar_gen) {
    const int tid  = threadIdx.x;
    const int lane = tid & 63;
    const int wave = tid >> 6;
    const int bid  = blockIdx.x;
    const int d    = bid / GPD;
    const int j0   = (bid % GPD) * C_ROWS;

    __shared__ float part[48][68];
    __shared__ float gsum[48];
    __shared__ float bh[48];
    __shared__ float gi_s[48];

    if (tid < 48) {
        int g = tid >> 4, jl = tid & 15;
        bh[tid] = bhh[d * G3 + g * 768 + j0 + jl];
    }

    // Load this WG's weight slice into registers: dot = wave + 4*m.
    float4 w[12][3];
    #pragma unroll
    for (int m = 0; m < 12; ++m) {
        int dot = wave + 4 * m;
        int g = dot >> 4, jl = dot & 15;
        const float* wrow = whh + (size_t)d * G3 * HDIM
                                + (size_t)(g * 768 + j0 + jl) * HDIM;
        #pragma unroll
        for (int i = 0; i < 3; ++i)
            w[m][i] = *(const float4*)(wrow + i * 256 + lane * 4);
    }
    __syncthreads();

    for (int t = 0; t < T_STEPS; ++t) {
        const float* hsrc = (t == 0) ? h0 : ((t & 1) ? hb0 : hb1);
        float* hdst = (t & 1) ? hb1 : hb0;

        // Prefetch per-row operands (latency hidden behind dot phase).
        float giv = 0.0f, hpv = 0.0f;
        if (tid < 48) {
            int g = tid >> 4, jl = tid & 15;
            giv = Gi[((size_t)t * 2 + d) * G3 + g * 768 + j0 + jl];
        }
        if (tid < 16) hpv = hsrc[d * 768 + j0 + tid];

        // Load h fragment: lane holds h[i*256 + lane*4 .. +3], i=0..2.
        float4 h4[3];
        #pragma unroll
        for (int i = 0; i < 3; ++i)
            h4[i] = *(const float4*)(hsrc + d * 768 + i * 256 + lane * 4);

        // Dot phase: 12 dots per wave, per-lane partials to LDS.
        #pragma unroll
        for (int m = 0; m < 12; ++m) {
            float s = dot4(w[m][0], h4[0]) + dot4(w[m][1], h4[1])
                    + dot4(w[m][2], h4[2]);
            part[wave + 4 * m][lane] = s;
        }
        if (tid < 48) gi_s[tid] = giv;
        __syncthreads();

        // Reduce: 4 threads per dot, each sums 16 partials, then quad shuffle.
        if (tid < 192) {
            int dot = tid >> 2, q = tid & 3;
            const float* p = &part[dot][q * 16];
            float4 p0 = *(const float4*)(p + 0);
            float4 p1 = *(const float4*)(p + 4);
            float4 p2 = *(const float4*)(p + 8);
            float4 p3 = *(const float4*)(p + 12);
            float s = (p0.x + p0.y + p0.z + p0.w) + (p1.x + p1.y + p1.z + p1.w)
                    + (p2.x + p2.y + p2.z + p2.w) + (p3.x + p3.y + p3.z + p3.w);
            s += __shfl_xor(s, 1);
            s += __shfl_xor(s, 2);
            if (q == 0) gsum[dot] = s;
        }
        __syncthreads();

        // Gate update for the 16 owned rows.
        if (tid < 16) {
            float pre_r = gi_s[tid]      + gsum[tid]      + bh[tid];
            float pre_z = gi_s[16 + tid] + gsum[16 + tid] + bh[16 + tid];
            float ghb_n =                  gsum[32 + tid] + bh[32 + tid];
            float gi_n  = gi_s[32 + tid];
            float r = sigf(pre_r);
            float z = sigf(pre_z);
            float n = tanhf(gi_n + r * ghb_n);
            float hn = (1.0f - z) * n + z * hpv;
            hdst[d * 768 + j0 + tid] = hn;
            Hout[((size_t)t * 2 + d) * 768 + j0 + tid] = hn;
        }
        __syncthreads();

        // Grid barrier: monotone counter + generation word (agent scope).
        if (tid == 0) {
            unsigned old = __hip_atomic_fetch_add(bar_cnt, 1u, __ATOMIC_ACQ_REL,
                                                  __HIP_MEMORY_SCOPE_AGENT);
            if (old == (unsigned)NWG * (unsigned)(t + 1) - 1u) {
                __hip_atomic_store(bar_gen, (unsigned)(t + 1), __ATOMIC_RELEASE,
                                   __HIP_MEMORY_SCOPE_AGENT);
            }
            while (__hip_atomic_load(bar_gen, __ATOMIC_ACQUIRE,
                                     __HIP_MEMORY_SCOPE_AGENT) < (unsigned)(t + 1)) {
            }
        }
        __syncthreads();
    }
}

// ---------------------------------------------------------------------------
// Final FC + sigmoid: out[r] = sigmoid(fc_w[r] . hin + fc_b[r]), 256 rows.
// One wave per row.
// ---------------------------------------------------------------------------
__global__ __launch_bounds__(64)
void fc_sig(const float* __restrict__ hin, const float* __restrict__ fw,
            const float* __restrict__ fb, float* __restrict__ out) {
    const int lane = threadIdx.x;
    const int row  = blockIdx.x;
    const float* wr = fw + (size_t)row * HC;
    float acc = 0.0f;
    #pragma unroll
    for (int i = 0; i < 6; ++i) {
        float4 w4 = *(const float4*)(wr  + i * 256 + lane * 4);
        float4 h4 = *(const float4*)(hin + i * 256 + lane * 4);
        acc += dot4(w4, h4);
    }
    #pragma unroll
    for (int s = 1; s < 64; s <<= 1) acc += __shfl_xor(acc, s);
    if (lane == 0) out[row] = sigf(acc + fb[row]);
}

// ---------------------------------------------------------------------------
extern "C" void kernel_launch(void* const* d_in, const int* in_sizes, int n_in,
                              void* d_out, int out_size, void* d_ws, size_t ws_size,
                              hipStream_t stream) {
    (void)in_sizes; (void)n_in; (void)out_size; (void)ws_size;

    const float* x     = (const float*)d_in[0];   // [8192,512]
    const float* h0    = (const float*)d_in[1];   // [4,768]
    const float* w_ih0 = (const float*)d_in[2];   // [2,2304,512]
    const float* w_hh0 = (const float*)d_in[3];   // [2,2304,768]
    const float* b_ih0 = (const float*)d_in[4];   // [2,2304]
    const float* b_hh0 = (const float*)d_in[5];
    const float* w_ih1 = (const float*)d_in[6];   // [2,2304,1536]
    const float* w_hh1 = (const float*)d_in[7];
    const float* b_ih1 = (const float*)d_in[8];
    const float* b_hh1 = (const float*)d_in[9];
    const float* fc_w  = (const float*)d_in[10];  // [256,1536]
    const float* fc_b  = (const float*)d_in[11];  // [256]
    float* out = (float*)d_out;

    char* ws = (char*)d_ws;
    unsigned* bar = (unsigned*)ws;               // 1 KiB: 4 x 256B-spaced words
    float* hb   = (float*)(ws + 1024);           // 4 ping/pong h buffers [2][768]
    float* Gi   = (float*)(ws + 32768);          // [8192][4608] fp32 = 144 MiB
    size_t gi_bytes = (size_t)T_STEPS * NDR * sizeof(float);
    float* Hout = (float*)(ws + 32768 + gi_bytes); // [8192][2][768] = 48 MiB

    // Barrier words must start at 0 every call (ws is poisoned 0xAA).
    hipMemsetAsync(ws, 0, 1024, stream);

    dim3 ggrid(NDR / 128, T_STEPS / 128);  // (36, 64)

    // Phase 1: Gi0 = x @ w_ih0^T + b_ih0
    gemm_xwt<<<ggrid, 256, 0, stream>>>(x, w_ih0, b_ih0, Gi, T_STEPS, NDR, 512);
    // Phase 2: layer-0 recurrence, store all h0[t]
    gru_rec<<<NWG, 256, 0, stream>>>(Gi, w_hh0, b_hh0, h0,
                                     hb, hb + HC, Hout, bar + 0, bar + 64);
    // Phase 3: Gi1 = concat_h0 @ w_ih1^T + b_ih1
    gemm_xwt<<<ggrid, 256, 0, stream>>>(Hout, w_ih1, b_ih1, Gi, T_STEPS, NDR, HC);
    // Phase 4: layer-1 recurrence (Hout reused; only last step consumed)
    gru_rec<<<NWG, 256, 0, stream>>>(Gi, w_hh1, b_hh1, h0 + 2 * HDIM,
                                     hb + 2 * HC, hb + 3 * HC, Hout,
                                     bar + 128, bar + 192);
    // Phase 5: y = sigmoid(fc_w @ h_last + fc_b)
    fc_sig<<<256, 64, 0, stream>>>(Hout + (size_t)(T_STEPS - 1) * HC,
                                   fc_w, fc_b, out);
}

// Round 2
// 63322.943 us; speedup vs baseline: 1.6651x; 1.6651x over previous
//
#include <hip/hip_runtime.h>
#include <cstdint>

#define T_STEPS 8192
#define HDIM    768
#define G3      2304   // 3*H
#define NDR     4608   // 2*3*H
#define HC      1536   // 2*H
#define NWG     96     // 2 dirs x 48 WGs (independent cliques, no cross-dir sync)
#define GPD     48     // workgroups per direction
#define C_ROWS  16     // h-rows per workgroup
#define LINE_F  32     // floats per exchange line (128 B): 16 h + tag + pad

// ---------------------------------------------------------------------------
// GEMM: C[m][n] = sum_k X[m][k] * W[n][k] + bias[n]
// X: [M,K] row-major, W: [N,K] row-major. 128x128 tile, BK=16, 256 thr, 8x8.
// ---------------------------------------------------------------------------
__global__ __launch_bounds__(256)
void gemm_xwt(const float* __restrict__ X, const float* __restrict__ W,
              const float* __restrict__ bias, float* __restrict__ C,
              int M, int N, int K) {
    __shared__ float As[16][132];
    __shared__ float Bs[16][132];
    const int tid = threadIdx.x;
    const int m0 = blockIdx.y * 128;
    const int n0 = blockIdx.x * 128;
    const int tm = tid >> 4;
    const int tn = tid & 15;

    float acc[8][8] = {};

    for (int k0 = 0; k0 < K; k0 += 16) {
        #pragma unroll
        for (int l = 0; l < 2; ++l) {
            int idx = l * 256 + tid;
            int row = idx >> 2;
            int kc  = (idx & 3) << 2;
            float4 a = *(const float4*)(X + (size_t)(m0 + row) * K + k0 + kc);
            As[kc + 0][row] = a.x; As[kc + 1][row] = a.y;
            As[kc + 2][row] = a.z; As[kc + 3][row] = a.w;
            float4 b = *(const float4*)(W + (size_t)(n0 + row) * K + k0 + kc);
            Bs[kc + 0][row] = b.x; Bs[kc + 1][row] = b.y;
            Bs[kc + 2][row] = b.z; Bs[kc + 3][row] = b.w;
        }
        __syncthreads();
        #pragma unroll
        for (int k = 0; k < 16; ++k) {
            float4 a0 = *(const float4*)&As[k][tm * 8];
            float4 a1 = *(const float4*)&As[k][tm * 8 + 4];
            float4 b0 = *(const float4*)&Bs[k][tn * 8];
            float4 b1 = *(const float4*)&Bs[k][tn * 8 + 4];
            float av[8] = {a0.x, a0.y, a0.z, a0.w, a1.x, a1.y, a1.z, a1.w};
            float bv[8] = {b0.x, b0.y, b0.z, b0.w, b1.x, b1.y, b1.z, b1.w};
            #pragma unroll
            for (int i = 0; i < 8; ++i)
                #pragma unroll
                for (int j = 0; j < 8; ++j)
                    acc[i][j] = fmaf(av[i], bv[j], acc[i][j]);
        }
        __syncthreads();
    }

    float bfrag[8];
    #pragma unroll
    for (int j = 0; j < 8; ++j) bfrag[j] = bias[n0 + tn * 8 + j];

    #pragma unroll
    for (int i = 0; i < 8; ++i) {
        float* cp = C + (size_t)(m0 + tm * 8 + i) * N + n0 + tn * 8;
        float4 o0, o1;
        o0.x = acc[i][0] + bfrag[0]; o0.y = acc[i][1] + bfrag[1];
        o0.z = acc[i][2] + bfrag[2]; o0.w = acc[i][3] + bfrag[3];
        o1.x = acc[i][4] + bfrag[4]; o1.y = acc[i][5] + bfrag[5];
        o1.z = acc[i][6] + bfrag[6]; o1.w = acc[i][7] + bfrag[7];
        *(float4*)(cp + 0) = o0;
        *(float4*)(cp + 4) = o1;
    }
}

// ---------------------------------------------------------------------------
// GRU recurrence, one layer, both directions. 96 WGs = 2 independent cliques
// of 48 (one per direction). NO central barrier: all-to-all tagged-line
// dataflow. Each WG owns 16 h-rows; per step it writes them to a 128-B line
// {16 floats, tag} (parity ping-pong) with a release-store tag; consumers
// poll the 48 tags of their direction, acquire-fence, gather h into LDS.
// Tag monotonicity + consume-before-produce dependency makes parity reuse
// safe (producer reaches t+2 only after all consumers tagged t+1, which
// implies they finished reading the parity-t lines).
// ---------------------------------------------------------------------------
__device__ __forceinline__ float dot4(float4 a, float4 b) {
    return a.x * b.x + a.y * b.y + a.z * b.z + a.w * b.w;
}
__device__ __forceinline__ float sigf(float x) {
    return 1.0f / (1.0f + expf(-x));
}

__global__ __launch_bounds__(256, 1)
void gru_rec(const float* __restrict__ Gi,   // [T][2][2304]
             const float* __restrict__ whh,  // [2][2304][768]
             const float* __restrict__ bhh,  // [2][2304]
             const float* __restrict__ h0,   // [2][768] (layer slice)
             float* __restrict__ exch,       // [2 parity][2 dir][48][32] floats
             float* __restrict__ Hout) {     // [T][2][768]
    const int tid  = threadIdx.x;
    const int lane = tid & 63;
    const int wave = tid >> 6;
    const int bid  = blockIdx.x;
    const int d    = bid / GPD;
    const int cidx = bid % GPD;
    const int j0   = cidx * C_ROWS;

    __shared__ float part[48][68];
    __shared__ float gsum[48];
    __shared__ float bh[48];
    __shared__ float gi_s[48];
    __shared__ float hsh[768];      // h_{t-1} for this direction

    if (tid < 48) {
        int g = tid >> 4, jl = tid & 15;
        bh[tid] = bhh[d * G3 + g * 768 + j0 + jl];
    }

    // Register-resident recurrent weights: dot = wave + 4*m, 12 dots/wave.
    float4 w[12][3];
    #pragma unroll
    for (int m = 0; m < 12; ++m) {
        int dot = wave + 4 * m;
        int g = dot >> 4, jl = dot & 15;
        const float* wrow = whh + (size_t)d * G3 * HDIM
                                + (size_t)(g * 768 + j0 + jl) * HDIM;
        #pragma unroll
        for (int i = 0; i < 3; ++i)
            w[m][i] = *(const float4*)(wrow + i * 256 + lane * 4);
    }
    __syncthreads();

    for (int t = 0; t < T_STEPS; ++t) {
        // Prefetch Gi for this step (in flight during the poll).
        float giv = 0.0f;
        if (tid < 48) {
            int g = tid >> 4, jl = tid & 15;
            giv = Gi[((size_t)t * 2 + d) * G3 + g * 768 + j0 + jl];
        }

        // --- Exchange: bring h_{t-1} (768 floats) into LDS ---
        if (tid < 48) {           // wave 0 only
            if (t == 0) {
                const float* src = h0 + d * 768 + tid * 16;
                float4 v0 = *(const float4*)(src + 0);
                float4 v1 = *(const float4*)(src + 4);
                float4 v2 = *(const float4*)(src + 8);
                float4 v3 = *(const float4*)(src + 12);
                *(float4*)&hsh[tid * 16 + 0]  = v0;
                *(float4*)&hsh[tid * 16 + 4]  = v1;
                *(float4*)&hsh[tid * 16 + 8]  = v2;
                *(float4*)&hsh[tid * 16 + 12] = v3;
            } else {
                const int p = (t - 1) & 1;
                const float* rl = exch + (size_t)((p * 2 + d) * GPD + tid) * LINE_F;
                const unsigned* tg = (const unsigned*)(rl + 16);
                while (__hip_atomic_load(tg, __ATOMIC_RELAXED,
                                         __HIP_MEMORY_SCOPE_AGENT) < (unsigned)t) {
                }
                __builtin_amdgcn_fence(__ATOMIC_ACQUIRE, "agent");
                float4 v0 = *(const float4*)(rl + 0);
                float4 v1 = *(const float4*)(rl + 4);
                float4 v2 = *(const float4*)(rl + 8);
                float4 v3 = *(const float4*)(rl + 12);
                *(float4*)&hsh[tid * 16 + 0]  = v0;
                *(float4*)&hsh[tid * 16 + 4]  = v1;
                *(float4*)&hsh[tid * 16 + 8]  = v2;
                *(float4*)&hsh[tid * 16 + 12] = v3;
            }
        }
        __syncthreads();

        // --- Dot phase: h from LDS, weights in registers ---
        float4 h4[3];
        #pragma unroll
        for (int i = 0; i < 3; ++i)
            h4[i] = *(const float4*)&hsh[i * 256 + lane * 4];

        #pragma unroll
        for (int m = 0; m < 12; ++m) {
            float s = dot4(w[m][0], h4[0]) + dot4(w[m][1], h4[1])
                    + dot4(w[m][2], h4[2]);
            part[wave + 4 * m][lane] = s;
        }
        if (tid < 48) gi_s[tid] = giv;
        __syncthreads();

        // --- Reduce: 4 threads per dot ---
        if (tid < 192) {
            int dot = tid >> 2, q = tid & 3;
            const float* p = &part[dot][q * 16];
            float4 p0 = *(const float4*)(p + 0);
            float4 p1 = *(const float4*)(p + 4);
            float4 p2 = *(const float4*)(p + 8);
            float4 p3 = *(const float4*)(p + 12);
            float s = (p0.x + p0.y + p0.z + p0.w) + (p1.x + p1.y + p1.z + p1.w)
                    + (p2.x + p2.y + p2.z + p2.w) + (p3.x + p3.y + p3.z + p3.w);
            s += __shfl_xor(s, 1);
            s += __shfl_xor(s, 2);
            if (q == 0) gsum[dot] = s;
        }
        __syncthreads();

        // --- Gates + publish (wave 0, lanes 0..15) ---
        if (tid < 16) {
            float hpv   = hsh[j0 + tid];
            float pre_r = gi_s[tid]      + gsum[tid]      + bh[tid];
            float pre_z = gi_s[16 + tid] + gsum[16 + tid] + bh[16 + tid];
            float ghb_n =                  gsum[32 + tid] + bh[32 + tid];
            float gi_n  = gi_s[32 + tid];
            float r = sigf(pre_r);
            float z = sigf(pre_z);
            float n = tanhf(gi_n + r * ghb_n);
            float hn = (1.0f - z) * n + z * hpv;
            float* line = exch + (size_t)(((t & 1) * 2 + d) * GPD + cidx) * LINE_F;
            line[tid] = hn;
            Hout[((size_t)t * 2 + d) * 768 + j0 + tid] = hn;
            if (tid == 0) {
                // Release: waits this wave's 16 line-stores, then tags.
                __hip_atomic_store((unsigned*)(line + 16), (unsigned)(t + 1),
                                   __ATOMIC_RELEASE, __HIP_MEMORY_SCOPE_AGENT);
            }
        }
        __syncthreads();
    }
}

// ---------------------------------------------------------------------------
// Final FC + sigmoid: out[r] = sigmoid(fc_w[r] . hin + fc_b[r]); one wave/row.
// ---------------------------------------------------------------------------
__global__ __launch_bounds__(64)
void fc_sig(const float* __restrict__ hin, const float* __restrict__ fw,
            const float* __restrict__ fb, float* __restrict__ out) {
    const int lane = threadIdx.x;
    const int row  = blockIdx.x;
    const float* wr = fw + (size_t)row * HC;
    float acc = 0.0f;
    #pragma unroll
    for (int i = 0; i < 6; ++i) {
        float4 w4 = *(const float4*)(wr  + i * 256 + lane * 4);
        float4 h4 = *(const float4*)(hin + i * 256 + lane * 4);
        acc += dot4(w4, h4);
    }
    #pragma unroll
    for (int s = 1; s < 64; s <<= 1) acc += __shfl_xor(acc, s);
    if (lane == 0) out[row] = sigf(acc + fb[row]);
}

// ---------------------------------------------------------------------------
extern "C" void kernel_launch(void* const* d_in, const int* in_sizes, int n_in,
                              void* d_out, int out_size, void* d_ws, size_t ws_size,
                              hipStream_t stream) {
    (void)in_sizes; (void)n_in; (void)out_size; (void)ws_size;

    const float* x     = (const float*)d_in[0];   // [8192,512]
    const float* h0    = (const float*)d_in[1];   // [4,768]
    const float* w_ih0 = (const float*)d_in[2];   // [2,2304,512]
    const float* w_hh0 = (const float*)d_in[3];   // [2,2304,768]
    const float* b_ih0 = (const float*)d_in[4];   // [2,2304]
    const float* b_hh0 = (const float*)d_in[5];
    const float* w_ih1 = (const float*)d_in[6];   // [2,2304,1536]
    const float* w_hh1 = (const float*)d_in[7];
    const float* b_ih1 = (const float*)d_in[8];
    const float* b_hh1 = (const float*)d_in[9];
    const float* fc_w  = (const float*)d_in[10];  // [256,1536]
    const float* fc_b  = (const float*)d_in[11];  // [256]
    float* out = (float*)d_out;

    char* ws = (char*)d_ws;
    // Exchange buffers: tags must start at 0 -> memset the first 64 KiB.
    float* exch0 = (float*)(ws + 4096);            // 2*2*48*128 B = 24 KiB
    float* exch1 = (float*)(ws + 4096 + 24576);    // layer 1's own region
    float* Gi    = (float*)(ws + 65536);           // [8192][4608] fp32 = 144 MiB
    size_t gi_bytes = (size_t)T_STEPS * NDR * sizeof(float);
    float* Hout  = (float*)(ws + 65536 + gi_bytes); // [8192][2][768] = 48 MiB

    hipMemsetAsync(ws, 0, 65536, stream);

    dim3 ggrid(NDR / 128, T_STEPS / 128);  // (36, 64)

    // Phase 1: Gi0 = x @ w_ih0^T + b_ih0
    gemm_xwt<<<ggrid, 256, 0, stream>>>(x, w_ih0, b_ih0, Gi, T_STEPS, NDR, 512);
    // Phase 2: layer-0 recurrence, store all h0[t]
    gru_rec<<<NWG, 256, 0, stream>>>(Gi, w_hh0, b_hh0, h0, exch0, Hout);
    // Phase 3: Gi1 = concat_h0 @ w_ih1^T + b_ih1
    gemm_xwt<<<ggrid, 256, 0, stream>>>(Hout, w_ih1, b_ih1, Gi, T_STEPS, NDR, HC);
    // Phase 4: layer-1 recurrence
    gru_rec<<<NWG, 256, 0, stream>>>(Gi, w_hh1, b_hh1, h0 + 2 * HDIM, exch1, Hout);
    // Phase 5: y = sigmoid(fc_w @ h_last + fc_b)
    fc_sig<<<256, 64, 0, stream>>>(Hout + (size_t)(T_STEPS - 1) * HC,
                                   fc_w, fc_b, out);
}

// Round 3
// 43879.044 us; speedup vs baseline: 2.4030x; 1.4431x over previous
//
#include <hip/hip_runtime.h>
#include <cstdint>

#define T_STEPS 8192
#define HDIM    768
#define G3      2304   // 3*H
#define NDR     4608   // 2*3*H
#define HC      1536   // 2*H
#define NWG     96     // 2 dirs x 48 WGs (independent cliques)
#define GPD     48     // workgroups per direction
#define C_ROWS  16     // h-rows per workgroup
#define LINE_P  16     // pairs per producer line (16 x 8 B = 128 B)

// ---------------------------------------------------------------------------
// GEMM: C[m][n] = sum_k X[m][k] * W[n][k] + bias[n]
// X: [M,K] row-major, W: [N,K] row-major. 128x128 tile, BK=16, 256 thr, 8x8.
// ---------------------------------------------------------------------------
__global__ __launch_bounds__(256)
void gemm_xwt(const float* __restrict__ X, const float* __restrict__ W,
              const float* __restrict__ bias, float* __restrict__ C,
              int M, int N, int K) {
    __shared__ float As[16][132];
    __shared__ float Bs[16][132];
    const int tid = threadIdx.x;
    const int m0 = blockIdx.y * 128;
    const int n0 = blockIdx.x * 128;
    const int tm = tid >> 4;
    const int tn = tid & 15;

    float acc[8][8] = {};

    for (int k0 = 0; k0 < K; k0 += 16) {
        #pragma unroll
        for (int l = 0; l < 2; ++l) {
            int idx = l * 256 + tid;
            int row = idx >> 2;
            int kc  = (idx & 3) << 2;
            float4 a = *(const float4*)(X + (size_t)(m0 + row) * K + k0 + kc);
            As[kc + 0][row] = a.x; As[kc + 1][row] = a.y;
            As[kc + 2][row] = a.z; As[kc + 3][row] = a.w;
            float4 b = *(const float4*)(W + (size_t)(n0 + row) * K + k0 + kc);
            Bs[kc + 0][row] = b.x; Bs[kc + 1][row] = b.y;
            Bs[kc + 2][row] = b.z; Bs[kc + 3][row] = b.w;
        }
        __syncthreads();
        #pragma unroll
        for (int k = 0; k < 16; ++k) {
            float4 a0 = *(const float4*)&As[k][tm * 8];
            float4 a1 = *(const float4*)&As[k][tm * 8 + 4];
            float4 b0 = *(const float4*)&Bs[k][tn * 8];
            float4 b1 = *(const float4*)&Bs[k][tn * 8 + 4];
            float av[8] = {a0.x, a0.y, a0.z, a0.w, a1.x, a1.y, a1.z, a1.w};
            float bv[8] = {b0.x, b0.y, b0.z, b0.w, b1.x, b1.y, b1.z, b1.w};
            #pragma unroll
            for (int i = 0; i < 8; ++i)
                #pragma unroll
                for (int j = 0; j < 8; ++j)
                    acc[i][j] = fmaf(av[i], bv[j], acc[i][j]);
        }
        __syncthreads();
    }

    float bfrag[8];
    #pragma unroll
    for (int j = 0; j < 8; ++j) bfrag[j] = bias[n0 + tn * 8 + j];

    #pragma unroll
    for (int i = 0; i < 8; ++i) {
        float* cp = C + (size_t)(m0 + tm * 8 + i) * N + n0 + tn * 8;
        float4 o0, o1;
        o0.x = acc[i][0] + bfrag[0]; o0.y = acc[i][1] + bfrag[1];
        o0.z = acc[i][2] + bfrag[2]; o0.w = acc[i][3] + bfrag[3];
        o1.x = acc[i][4] + bfrag[4]; o1.y = acc[i][5] + bfrag[5];
        o1.z = acc[i][6] + bfrag[6]; o1.w = acc[i][7] + bfrag[7];
        *(float4*)(cp + 0) = o0;
        *(float4*)(cp + 4) = o1;
    }
}

// ---------------------------------------------------------------------------
// GRU recurrence, one layer, both directions. 96 WGs = 2 cliques of 48.
// ONE-round-trip exchange: each h element travels as an atomic 8-B pair
// (fp32 value ‖ step tag). Producer: 16 relaxed agent-scope 8-B stores.
// Consumer: lane i (i<48) batch-issues 16 relaxed atomic loads of producer
// i's line, accepts when all tags >= t. Pair atomicity replaces
// release/acquire; no fences anywhere on the step path.
// Parity ping-pong; overwrite-safety: producer reaches step t+2 only after
// consuming step-t+1 pairs, which requires every consumer to have finished
// reading its step-t+1 line, so polled tags are always in {t-2, t}.
// ---------------------------------------------------------------------------
__device__ __forceinline__ float dot4(float4 a, float4 b) {
    return a.x * b.x + a.y * b.y + a.z * b.z + a.w * b.w;
}
__device__ __forceinline__ float sigf(float x) {
    return 1.0f / (1.0f + expf(-x));
}

__global__ __launch_bounds__(256, 1)
void gru_rec(const float* __restrict__ Gi,   // [T][2][2304]
             const float* __restrict__ whh,  // [2][2304][768]
             const float* __restrict__ bhh,  // [2][2304]
             const float* __restrict__ h0,   // [2][768] (layer slice)
             unsigned long long* __restrict__ exch, // [2 par][2 dir][48][16] pairs
             float* __restrict__ Hout) {     // [T][2][768]
    const int tid  = threadIdx.x;
    const int lane = tid & 63;
    const int wave = tid >> 6;
    const int bid  = blockIdx.x;
    const int d    = bid / GPD;
    const int cidx = bid % GPD;
    const int j0   = cidx * C_ROWS;

    __shared__ float part[48][68];
    __shared__ float gsum[48];
    __shared__ float bh[48];
    __shared__ float gi_s[48];
    __shared__ float hsh[768];      // h_{t-1} for this direction

    if (tid < 48) {
        int g = tid >> 4, jl = tid & 15;
        bh[tid] = bhh[d * G3 + g * 768 + j0 + jl];
    }

    // Register-resident recurrent weights: dot = wave + 4*m, 12 dots/wave.
    float4 w[12][3];
    #pragma unroll
    for (int m = 0; m < 12; ++m) {
        int dot = wave + 4 * m;
        int g = dot >> 4, jl = dot & 15;
        const float* wrow = whh + (size_t)d * G3 * HDIM
                                + (size_t)(g * 768 + j0 + jl) * HDIM;
        #pragma unroll
        for (int i = 0; i < 3; ++i)
            w[m][i] = *(const float4*)(wrow + i * 256 + lane * 4);
    }
    __syncthreads();

    for (int t = 0; t < T_STEPS; ++t) {
        // Prefetch Gi for this step (in flight during the poll).
        float giv = 0.0f;
        if (tid < 48) {
            int g = tid >> 4, jl = tid & 15;
            giv = Gi[((size_t)t * 2 + d) * G3 + g * 768 + j0 + jl];
        }

        // --- Exchange: bring h_{t-1} (768 floats) into LDS, one round trip ---
        if (tid < 48) {           // wave 0: lane i gathers producer i's 16 rows
            float hv[LINE_P];
            if (t == 0) {
                const float* src = h0 + d * 768 + tid * 16;
                #pragma unroll
                for (int i = 0; i < LINE_P; ++i) hv[i] = src[i];
            } else {
                const unsigned long long* src =
                    exch + (size_t)((((t - 1) & 1) * 2 + d) * GPD + tid) * LINE_P;
                unsigned long long v[LINE_P];
                for (;;) {
                    #pragma unroll
                    for (int i = 0; i < LINE_P; ++i)
                        v[i] = __hip_atomic_load(src + i, __ATOMIC_RELAXED,
                                                 __HIP_MEMORY_SCOPE_AGENT);
                    bool ok = true;
                    #pragma unroll
                    for (int i = 0; i < LINE_P; ++i)
                        ok &= ((unsigned)v[i] >= (unsigned)t);
                    if (ok) break;
                }
                #pragma unroll
                for (int i = 0; i < LINE_P; ++i)
                    hv[i] = __uint_as_float((unsigned)(v[i] >> 32));
            }
            #pragma unroll
            for (int i = 0; i < LINE_P; ++i) hsh[tid * 16 + i] = hv[i];
        }
        __syncthreads();

        // --- Dot phase: h from LDS, weights in registers ---
        float4 h4[3];
        #pragma unroll
        for (int i = 0; i < 3; ++i)
            h4[i] = *(const float4*)&hsh[i * 256 + lane * 4];

        #pragma unroll
        for (int m = 0; m < 12; ++m) {
            float s = dot4(w[m][0], h4[0]) + dot4(w[m][1], h4[1])
                    + dot4(w[m][2], h4[2]);
            part[wave + 4 * m][lane] = s;
        }
        if (tid < 48) gi_s[tid] = giv;
        __syncthreads();

        // --- Reduce: 4 threads per dot ---
        if (tid < 192) {
            int dot = tid >> 2, q = tid & 3;
            const float* p = &part[dot][q * 16];
            float4 p0 = *(const float4*)(p + 0);
            float4 p1 = *(const float4*)(p + 4);
            float4 p2 = *(const float4*)(p + 8);
            float4 p3 = *(const float4*)(p + 12);
            float s = (p0.x + p0.y + p0.z + p0.w) + (p1.x + p1.y + p1.z + p1.w)
                    + (p2.x + p2.y + p2.z + p2.w) + (p3.x + p3.y + p3.z + p3.w);
            s += __shfl_xor(s, 1);
            s += __shfl_xor(s, 2);
            if (q == 0) gsum[dot] = s;
        }
        __syncthreads();

        // --- Gates + publish (wave 0, lanes 0..15) ---
        if (tid < 16) {
            float hpv   = hsh[j0 + tid];
            float pre_r = gi_s[tid]      + gsum[tid]      + bh[tid];
            float pre_z = gi_s[16 + tid] + gsum[16 + tid] + bh[16 + tid];
            float ghb_n =                  gsum[32 + tid] + bh[32 + tid];
            float gi_n  = gi_s[32 + tid];
            float r = sigf(pre_r);
            float z = sigf(pre_z);
            float n = tanhf(gi_n + r * ghb_n);
            float hn = (1.0f - z) * n + z * hpv;
            unsigned long long pair =
                ((unsigned long long)__float_as_uint(hn) << 32)
                | (unsigned long long)(unsigned)(t + 1);
            unsigned long long* line =
                exch + (size_t)(((t & 1) * 2 + d) * GPD + cidx) * LINE_P;
            __hip_atomic_store(line + tid, pair, __ATOMIC_RELAXED,
                               __HIP_MEMORY_SCOPE_AGENT);
            Hout[((size_t)t * 2 + d) * 768 + j0 + tid] = hn;
        }
        __syncthreads();
    }
}

// ---------------------------------------------------------------------------
// Final FC + sigmoid: out[r] = sigmoid(fc_w[r] . hin + fc_b[r]); one wave/row.
// ---------------------------------------------------------------------------
__global__ __launch_bounds__(64)
void fc_sig(const float* __restrict__ hin, const float* __restrict__ fw,
            const float* __restrict__ fb, float* __restrict__ out) {
    const int lane = threadIdx.x;
    const int row  = blockIdx.x;
    const float* wr = fw + (size_t)row * HC;
    float acc = 0.0f;
    #pragma unroll
    for (int i = 0; i < 6; ++i) {
        float4 w4 = *(const float4*)(wr  + i * 256 + lane * 4);
        float4 h4 = *(const float4*)(hin + i * 256 + lane * 4);
        acc += dot4(w4, h4);
    }
    #pragma unroll
    for (int s = 1; s < 64; s <<= 1) acc += __shfl_xor(acc, s);
    if (lane == 0) out[row] = sigf(acc + fb[row]);
}

// ---------------------------------------------------------------------------
extern "C" void kernel_launch(void* const* d_in, const int* in_sizes, int n_in,
                              void* d_out, int out_size, void* d_ws, size_t ws_size,
                              hipStream_t stream) {
    (void)in_sizes; (void)n_in; (void)out_size; (void)ws_size;

    const float* x     = (const float*)d_in[0];   // [8192,512]
    const float* h0    = (const float*)d_in[1];   // [4,768]
    const float* w_ih0 = (const float*)d_in[2];   // [2,2304,512]
    const float* w_hh0 = (const float*)d_in[3];   // [2,2304,768]
    const float* b_ih0 = (const float*)d_in[4];   // [2,2304]
    const float* b_hh0 = (const float*)d_in[5];
    const float* w_ih1 = (const float*)d_in[6];   // [2,2304,1536]
    const float* w_hh1 = (const float*)d_in[7];
    const float* b_ih1 = (const float*)d_in[8];
    const float* b_hh1 = (const float*)d_in[9];
    const float* fc_w  = (const float*)d_in[10];  // [256,1536]
    const float* fc_b  = (const float*)d_in[11];  // [256]
    float* out = (float*)d_out;

    char* ws = (char*)d_ws;
    // Exchange pair buffers: tags must start at 0 -> memset first 64 KiB.
    unsigned long long* exch0 = (unsigned long long*)(ws + 4096);  // 24 KiB
    unsigned long long* exch1 = (unsigned long long*)(ws + 4096 + 24576);
    float* Gi    = (float*)(ws + 65536);           // [8192][4608] fp32 = 144 MiB
    size_t gi_bytes = (size_t)T_STEPS * NDR * sizeof(float);
    float* Hout  = (float*)(ws + 65536 + gi_bytes); // [8192][2][768] = 48 MiB

    hipMemsetAsync(ws, 0, 65536, stream);

    dim3 ggrid(NDR / 128, T_STEPS / 128);  // (36, 64)

    // Phase 1: Gi0 = x @ w_ih0^T + b_ih0
    gemm_xwt<<<ggrid, 256, 0, stream>>>(x, w_ih0, b_ih0, Gi, T_STEPS, NDR, 512);
    // Phase 2: layer-0 recurrence, store all h0[t]
    gru_rec<<<NWG, 256, 0, stream>>>(Gi, w_hh0, b_hh0, h0, exch0, Hout);
    // Phase 3: Gi1 = concat_h0 @ w_ih1^T + b_ih1
    gemm_xwt<<<ggrid, 256, 0, stream>>>(Hout, w_ih1, b_ih1, Gi, T_STEPS, NDR, HC);
    // Phase 4: layer-1 recurrence
    gru_rec<<<NWG, 256, 0, stream>>>(Gi, w_hh1, b_hh1, h0 + 2 * HDIM, exch1, Hout);
    // Phase 5: y = sigmoid(fc_w @ h_last + fc_b)
    fc_sig<<<256, 64, 0, stream>>>(Hout + (size_t)(T_STEPS - 1) * HC,
                                   fc_w, fc_b, out);
}

// Round 4
// 41755.133 us; speedup vs baseline: 2.5252x; 1.0509x over previous
//
#include <hip/hip_runtime.h>
#include <cstdint>

#define T_STEPS 8192
#define HDIM    768
#define G3      2304   // 3*H
#define NDR     4608   // 2*3*H
#define HC      1536   // 2*H
#define GPD     96     // workgroups per direction
#define NWG     192    // 2 dirs x 96 WGs (independent cliques)
#define C_ROWS  8      // h-rows per workgroup
#define LINE_P  8      // pairs per producer line (8 x 8 B = 64 B)

// ---------------------------------------------------------------------------
// GEMM: C[m][n] = sum_k X[m][k] * W[n][k] + bias[n]
// X: [M,K] row-major, W: [N,K] row-major. 128x128 tile, BK=16, 256 thr, 8x8.
// ---------------------------------------------------------------------------
__global__ __launch_bounds__(256)
void gemm_xwt(const float* __restrict__ X, const float* __restrict__ W,
              const float* __restrict__ bias, float* __restrict__ C,
              int M, int N, int K) {
    __shared__ float As[16][132];
    __shared__ float Bs[16][132];
    const int tid = threadIdx.x;
    const int m0 = blockIdx.y * 128;
    const int n0 = blockIdx.x * 128;
    const int tm = tid >> 4;
    const int tn = tid & 15;

    float acc[8][8] = {};

    for (int k0 = 0; k0 < K; k0 += 16) {
        #pragma unroll
        for (int l = 0; l < 2; ++l) {
            int idx = l * 256 + tid;
            int row = idx >> 2;
            int kc  = (idx & 3) << 2;
            float4 a = *(const float4*)(X + (size_t)(m0 + row) * K + k0 + kc);
            As[kc + 0][row] = a.x; As[kc + 1][row] = a.y;
            As[kc + 2][row] = a.z; As[kc + 3][row] = a.w;
            float4 b = *(const float4*)(W + (size_t)(n0 + row) * K + k0 + kc);
            Bs[kc + 0][row] = b.x; Bs[kc + 1][row] = b.y;
            Bs[kc + 2][row] = b.z; Bs[kc + 3][row] = b.w;
        }
        __syncthreads();
        #pragma unroll
        for (int k = 0; k < 16; ++k) {
            float4 a0 = *(const float4*)&As[k][tm * 8];
            float4 a1 = *(const float4*)&As[k][tm * 8 + 4];
            float4 b0 = *(const float4*)&Bs[k][tn * 8];
            float4 b1 = *(const float4*)&Bs[k][tn * 8 + 4];
            float av[8] = {a0.x, a0.y, a0.z, a0.w, a1.x, a1.y, a1.z, a1.w};
            float bv[8] = {b0.x, b0.y, b0.z, b0.w, b1.x, b1.y, b1.z, b1.w};
            #pragma unroll
            for (int i = 0; i < 8; ++i)
                #pragma unroll
                for (int j = 0; j < 8; ++j)
                    acc[i][j] = fmaf(av[i], bv[j], acc[i][j]);
        }
        __syncthreads();
    }

    float bfrag[8];
    #pragma unroll
    for (int j = 0; j < 8; ++j) bfrag[j] = bias[n0 + tn * 8 + j];

    #pragma unroll
    for (int i = 0; i < 8; ++i) {
        float* cp = C + (size_t)(m0 + tm * 8 + i) * N + n0 + tn * 8;
        float4 o0, o1;
        o0.x = acc[i][0] + bfrag[0]; o0.y = acc[i][1] + bfrag[1];
        o0.z = acc[i][2] + bfrag[2]; o0.w = acc[i][3] + bfrag[3];
        o1.x = acc[i][4] + bfrag[4]; o1.y = acc[i][5] + bfrag[5];
        o1.z = acc[i][6] + bfrag[6]; o1.w = acc[i][7] + bfrag[7];
        *(float4*)(cp + 0) = o0;
        *(float4*)(cp + 4) = o1;
    }
}

// ---------------------------------------------------------------------------
// GRU recurrence, one layer, both directions. 192 WGs = 2 cliques of 96.
// Exchange: self-validating atomic 8-B pairs (fp32 value ‖ step tag),
// relaxed agent scope, one round trip. Each WG owns 8 h-rows (24 dots,
// 6/wave, 72 weight floats/lane -> register-resident). Poll lane i (<96)
// owns producer i's 64-B line. Parity ping-pong; overwrite-safety and the
// dropped trailing barrier both follow from: tag t+1 can only appear after
// every producer consumed every step-t line (incl. ours), which is ordered
// after our step-t hsh reads via true data dependency.
// ---------------------------------------------------------------------------
__device__ __forceinline__ float dot4(float4 a, float4 b) {
    return a.x * b.x + a.y * b.y + a.z * b.z + a.w * b.w;
}
__device__ __forceinline__ float sigf(float x) {
    return 1.0f / (1.0f + expf(-x));
}

__global__ __launch_bounds__(256, 1)
void gru_rec(const float* __restrict__ Gi,   // [T][2][2304]
             const float* __restrict__ whh,  // [2][2304][768]
             const float* __restrict__ bhh,  // [2][2304]
             const float* __restrict__ h0,   // [2][768] (layer slice)
             unsigned long long* __restrict__ exch, // [2 par][2 dir][96][8]
             float* __restrict__ Hout) {     // [T][2][768]
    const int tid  = threadIdx.x;
    const int lane = tid & 63;
    const int wave = tid >> 6;
    const int bid  = blockIdx.x;
    const int d    = bid / GPD;
    const int cidx = bid % GPD;
    const int j0   = cidx * C_ROWS;

    __shared__ float part[24][68];
    __shared__ float gsum[24];
    __shared__ float bh[24];
    __shared__ float gi_s[24];
    __shared__ float hsh[768];      // h_{t-1} for this direction

    if (tid < 24) {
        int g = tid >> 3, jl = tid & 7;
        bh[tid] = bhh[d * G3 + g * 768 + j0 + jl];
    }

    // Register-resident recurrent weights: dot = wave + 4*m, 6 dots/wave.
    float4 w[6][3];
    #pragma unroll
    for (int m = 0; m < 6; ++m) {
        int dot = wave + 4 * m;
        int g = dot >> 3, jl = dot & 7;
        const float* wrow = whh + (size_t)d * G3 * HDIM
                                + (size_t)(g * 768 + j0 + jl) * HDIM;
        #pragma unroll
        for (int i = 0; i < 3; ++i)
            w[m][i] = *(const float4*)(wrow + i * 256 + lane * 4);
    }
    __syncthreads();

    for (int t = 0; t < T_STEPS; ++t) {
        // Prefetch Gi for this step (in flight during the poll).
        float giv = 0.0f;
        if (tid < 24) {
            giv = Gi[((size_t)t * 2 + d) * G3 + (tid >> 3) * 768 + j0 + (tid & 7)];
        }

        // --- Exchange: h_{t-1} (768 floats) into LDS, one round trip ---
        if (tid < 96) {           // poll lane i gathers producer i's 8 rows
            float hv[LINE_P];
            if (t == 0) {
                const float* src = h0 + d * 768 + tid * 8;
                #pragma unroll
                for (int i = 0; i < LINE_P; ++i) hv[i] = src[i];
            } else {
                const unsigned long long* src =
                    exch + (size_t)((((t - 1) & 1) * 2 + d) * GPD + tid) * LINE_P;
                unsigned long long v[LINE_P];
                for (;;) {
                    #pragma unroll
                    for (int i = 0; i < LINE_P; ++i)
                        v[i] = __hip_atomic_load(src + i, __ATOMIC_RELAXED,
                                                 __HIP_MEMORY_SCOPE_AGENT);
                    bool ok = true;
                    #pragma unroll
                    for (int i = 0; i < LINE_P; ++i)
                        ok &= ((unsigned)v[i] >= (unsigned)t);
                    if (ok) break;
                }
                #pragma unroll
                for (int i = 0; i < LINE_P; ++i)
                    hv[i] = __uint_as_float((unsigned)(v[i] >> 32));
            }
            #pragma unroll
            for (int i = 0; i < LINE_P; ++i) hsh[tid * 8 + i] = hv[i];
        }
        __syncthreads();

        // --- Dot phase: h from LDS, weights in registers ---
        float4 h4[3];
        #pragma unroll
        for (int i = 0; i < 3; ++i)
            h4[i] = *(const float4*)&hsh[i * 256 + lane * 4];

        #pragma unroll
        for (int m = 0; m < 6; ++m) {
            float s = dot4(w[m][0], h4[0]) + dot4(w[m][1], h4[1])
                    + dot4(w[m][2], h4[2]);
            part[wave + 4 * m][lane] = s;
        }
        if (tid < 24) gi_s[tid] = giv;
        __syncthreads();

        // --- Reduce: 8 threads per dot (24 dots, 192 threads) ---
        if (tid < 192) {
            int dot = tid >> 3, o = tid & 7;
            const float* p = &part[dot][o * 8];
            float4 p0 = *(const float4*)(p + 0);
            float4 p1 = *(const float4*)(p + 4);
            float s = (p0.x + p0.y + p0.z + p0.w) + (p1.x + p1.y + p1.z + p1.w);
            s += __shfl_xor(s, 1);
            s += __shfl_xor(s, 2);
            s += __shfl_xor(s, 4);
            if (o == 0) gsum[dot] = s;
        }
        __syncthreads();

        // --- Gates + publish (wave 0, lanes 0..7) ---
        if (tid < 8) {
            float hpv   = hsh[j0 + tid];
            float pre_r = gi_s[tid]      + gsum[tid]      + bh[tid];
            float pre_z = gi_s[8 + tid]  + gsum[8 + tid]  + bh[8 + tid];
            float ghb_n =                  gsum[16 + tid] + bh[16 + tid];
            float gi_n  = gi_s[16 + tid];
            float r = sigf(pre_r);
            float z = sigf(pre_z);
            float n = tanhf(gi_n + r * ghb_n);
            float hn = (1.0f - z) * n + z * hpv;
            unsigned long long pair =
                ((unsigned long long)__float_as_uint(hn) << 32)
                | (unsigned long long)(unsigned)(t + 1);
            unsigned long long* line =
                exch + (size_t)(((t & 1) * 2 + d) * GPD + cidx) * LINE_P;
            __hip_atomic_store(line + tid, pair, __ATOMIC_RELAXED,
                               __HIP_MEMORY_SCOPE_AGENT);
            Hout[((size_t)t * 2 + d) * 768 + j0 + tid] = hn;
        }
        // no trailing __syncthreads(): any tag t+1 implies our step-t publish
        // (hence our hsh reads) completed — see header comment.
    }
}

// ---------------------------------------------------------------------------
// Final FC + sigmoid: out[r] = sigmoid(fc_w[r] . hin + fc_b[r]); one wave/row.
// ---------------------------------------------------------------------------
__global__ __launch_bounds__(64)
void fc_sig(const float* __restrict__ hin, const float* __restrict__ fw,
            const float* __restrict__ fb, float* __restrict__ out) {
    const int lane = threadIdx.x;
    const int row  = blockIdx.x;
    const float* wr = fw + (size_t)row * HC;
    float acc = 0.0f;
    #pragma unroll
    for (int i = 0; i < 6; ++i) {
        float4 w4 = *(const float4*)(wr  + i * 256 + lane * 4);
        float4 h4 = *(const float4*)(hin + i * 256 + lane * 4);
        acc += dot4(w4, h4);
    }
    #pragma unroll
    for (int s = 1; s < 64; s <<= 1) acc += __shfl_xor(acc, s);
    if (lane == 0) out[row] = sigf(acc + fb[row]);
}

// ---------------------------------------------------------------------------
extern "C" void kernel_launch(void* const* d_in, const int* in_sizes, int n_in,
                              void* d_out, int out_size, void* d_ws, size_t ws_size,
                              hipStream_t stream) {
    (void)in_sizes; (void)n_in; (void)out_size; (void)ws_size;

    const float* x     = (const float*)d_in[0];   // [8192,512]
    const float* h0    = (const float*)d_in[1];   // [4,768]
    const float* w_ih0 = (const float*)d_in[2];   // [2,2304,512]
    const float* w_hh0 = (const float*)d_in[3];   // [2,2304,768]
    const float* b_ih0 = (const float*)d_in[4];   // [2,2304]
    const float* b_hh0 = (const float*)d_in[5];
    const float* w_ih1 = (const float*)d_in[6];   // [2,2304,1536]
    const float* w_hh1 = (const float*)d_in[7];
    const float* b_ih1 = (const float*)d_in[8];
    const float* b_hh1 = (const float*)d_in[9];
    const float* fc_w  = (const float*)d_in[10];  // [256,1536]
    const float* fc_b  = (const float*)d_in[11];  // [256]
    float* out = (float*)d_out;

    char* ws = (char*)d_ws;
    // Exchange pair buffers (tags must start 0): 2*2*96*8*8 B = 24 KiB each.
    unsigned long long* exch0 = (unsigned long long*)(ws + 4096);
    unsigned long long* exch1 = (unsigned long long*)(ws + 4096 + 24576);
    float* Gi    = (float*)(ws + 65536);           // [8192][4608] fp32 = 144 MiB
    size_t gi_bytes = (size_t)T_STEPS * NDR * sizeof(float);
    float* Hout  = (float*)(ws + 65536 + gi_bytes); // [8192][2][768] = 48 MiB

    hipMemsetAsync(ws, 0, 65536, stream);

    dim3 ggrid(NDR / 128, T_STEPS / 128);  // (36, 64)

    // Phase 1: Gi0 = x @ w_ih0^T + b_ih0
    gemm_xwt<<<ggrid, 256, 0, stream>>>(x, w_ih0, b_ih0, Gi, T_STEPS, NDR, 512);
    // Phase 2: layer-0 recurrence, store all h0[t]
    gru_rec<<<NWG, 256, 0, stream>>>(Gi, w_hh0, b_hh0, h0, exch0, Hout);
    // Phase 3: Gi1 = concat_h0 @ w_ih1^T + b_ih1
    gemm_xwt<<<ggrid, 256, 0, stream>>>(Hout, w_ih1, b_ih1, Gi, T_STEPS, NDR, HC);
    // Phase 4: layer-1 recurrence
    gru_rec<<<NWG, 256, 0, stream>>>(Gi, w_hh1, b_hh1, h0 + 2 * HDIM, exch1, Hout);
    // Phase 5: y = sigmoid(fc_w @ h_last + fc_b)
    fc_sig<<<256, 64, 0, stream>>>(Hout + (size_t)(T_STEPS - 1) * HC,
                                   fc_w, fc_b, out);
}